// Round 4
// baseline (643.619 us; speedup 1.0000x reference)
//
#include <hip/hip_runtime.h>
#include <hip/hip_bf16.h>
#include <math.h>

// Problem constants
#define N_      4
#define L_      256
#define M_      2
#define D_      768
#define H_      12
#define FF_     3072
#define DH_     64
#define LAYERS_ 4
#define BASE_   8          // N*M
#define T_      1032       // BASE_ + N*L
#define TP_     1152       // T_ padded to multiple of 128
#define KK_     258        // M + L
#define QS_     2304       // fused q|k|v row stride
#define PS_     264        // P LDS row stride (bf16): 2-way bank alias only (free)

typedef __bf16 bf16x8 __attribute__((ext_vector_type(8)));
typedef float  f32x4  __attribute__((ext_vector_type(4)));

__device__ __forceinline__ void async_load16(const __hip_bfloat16* g, __hip_bfloat16* l) {
  __builtin_amdgcn_global_load_lds(
      (const __attribute__((address_space(1))) unsigned int*)g,
      (__attribute__((address_space(3))) unsigned int*)l, 16, 0, 0);
}

// ---------------------------------------------------------------------------
// Batched transpose+cast: dst[N,K]bf16 = T(src[K,N]fp32). One 32x32 tile per
// block; bf16x2 paired stores. Grid: (N/32, K/32, batch).
// ---------------------------------------------------------------------------
__device__ __forceinline__ void tile_transpose(
    const float* __restrict__ src, __hip_bfloat16* __restrict__ dst, int K, int N) {
  __shared__ float tile[32][33];
  const int k0 = blockIdx.y * 32, n0 = blockIdx.x * 32;
  const int r = threadIdx.x >> 5, c = threadIdx.x & 31;
  #pragma unroll
  for (int i = 0; i < 4; ++i)
    tile[r + i * 8][c] = src[(size_t)(k0 + r + i * 8) * N + n0 + c];
  __syncthreads();
  #pragma unroll
  for (int i = 0; i < 2; ++i) {
    int e = threadIdx.x + i * 256;
    int n = e >> 4, kp = e & 15;
    __hip_bfloat162 v;
    v.x = __float2bfloat16(tile[2 * kp][n]);
    v.y = __float2bfloat16(tile[2 * kp + 1][n]);
    *(__hip_bfloat162*)&dst[(size_t)(n0 + n) * K + k0 + 2 * kp] = v;
  }
}

// QKV weights: 12 matrices 768x768. z = layer*3 + {q,k,v}
__global__ __launch_bounds__(256) void prep_qkv_kernel(
    const float* __restrict__ Wq, const float* __restrict__ Wk,
    const float* __restrict__ Wv, __hip_bfloat16* __restrict__ Wqkvt) {
  const int z = blockIdx.z, layer = z / 3, which = z - layer * 3;
  const float* src = (which == 0 ? Wq : which == 1 ? Wk : Wv) + (size_t)layer * D_ * D_;
  __hip_bfloat16* dst = Wqkvt + (size_t)layer * QS_ * D_ + (size_t)which * D_ * D_;
  tile_transpose(src, dst, D_, D_);
}

// W1: 4 matrices [768,3072] -> [3072][768]
__global__ __launch_bounds__(256) void prep_w1_kernel(
    const float* __restrict__ W1, __hip_bfloat16* __restrict__ W1t) {
  const int z = blockIdx.z;
  tile_transpose(W1 + (size_t)z * D_ * FF_, W1t + (size_t)z * FF_ * D_, D_, FF_);
}

// W2: 4 matrices [3072,768] -> [768][3072]
__global__ __launch_bounds__(256) void prep_w2_kernel(
    const float* __restrict__ W2, __hip_bfloat16* __restrict__ W2t) {
  const int z = blockIdx.z;
  tile_transpose(W2 + (size_t)z * FF_ * D_, W2t + (size_t)z * D_ * FF_, FF_, D_);
}

__global__ __launch_bounds__(256) void pack_bias_kernel(
    const float* __restrict__ bq, const float* __restrict__ bk,
    const float* __restrict__ bv, float* __restrict__ out) {
  int i = blockIdx.x * 256 + threadIdx.x;
  int l = i / QS_, j = i - l * QS_;
  float v;
  if (j < D_)            v = bq[l * D_ + j];
  else if (j < 2 * D_)   v = bk[l * D_ + (j - D_)];
  else                   v = bv[l * D_ + (j - 2 * D_)];
  out[i] = v;
}

// ---------------------------------------------------------------------------
__global__ __launch_bounds__(256) void embed_kernel(
    const int* __restrict__ ids, const float* __restrict__ memory,
    const float* __restrict__ emb, const float* __restrict__ pos,
    float* __restrict__ x, __hip_bfloat16* __restrict__ xb) {
  int row = blockIdx.x;
  const float *src, *p;
  if (row < BASE_) {
    src = memory + (long long)row * D_;
    p   = pos + (row & 1) * D_;
  } else {
    int i = row - BASE_;
    int tok = ids[i];
    src = emb + (long long)tok * D_;
    p   = pos + (M_ + (i & (L_ - 1))) * D_;
  }
  for (int d = threadIdx.x; d < D_; d += 256) {
    float v = src[d] + p[d];
    x[(long long)row * D_ + d]  = v;
    xb[(long long)row * D_ + d] = __float2bfloat16(v);
  }
}

// ---------------------------------------------------------------------------
// 128x128 MFMA GEMM: C = A[MP,K] @ Bt[N,K]^T + bias. BK=64 (2 slabs of 32),
// 4 waves in 2x2, each wave 64x64 (4x4 of 16x16 tiles, 32 MFMA per K-iter).
// WOUT: 0 = bf16, 1 = fp32, 2 = bf16 + transposed-V split (QKV layout).
// ---------------------------------------------------------------------------
template <int ACT, int WOUT>
__global__ __launch_bounds__(256) void gemm_mfma128(
    const __hip_bfloat16* __restrict__ A,   // [MP,K]
    const __hip_bfloat16* __restrict__ Bt,  // [N,K]
    const float* __restrict__ bias,         // [N]
    float* __restrict__ C,                  // fp32 out (WOUT==1)
    __hip_bfloat16* __restrict__ Cb,        // bf16 out (WOUT==0,2)
    __hip_bfloat16* __restrict__ vt,        // [768][TP_] (WOUT==2)
    int N, int K) {
  __shared__ __align__(16) __hip_bfloat16 As[2][128][32];
  __shared__ __align__(16) __hip_bfloat16 Bs[2][128][32];
  const int tid  = threadIdx.x;
  const int lane = tid & 63, wid = tid >> 6;
  const int ln   = lane & 15, qd = lane >> 4;
  const int wm   = wid >> 1, wn = wid & 1;
  const int lr   = lane >> 2;          // row within 16-row staging chunk
  const int lc   = (lane & 3) * 8;     // k offset (8 bf16 = 16B)

  f32x4 acc[4][4] = {};
  for (int k0 = 0; k0 < K; k0 += 64) {
    #pragma unroll
    for (int s = 0; s < 2; ++s) {
      #pragma unroll
      for (int i = 0; i < 2; ++i) {
        const int rr = wid * 16 + i * 64 + lr;
        async_load16(A  + (size_t)(blockIdx.y * 128 + rr) * K + k0 + s * 32 + lc,
                     &As[s][wid * 16 + i * 64][0]);
        async_load16(Bt + (size_t)(blockIdx.x * 128 + rr) * K + k0 + s * 32 + lc,
                     &Bs[s][wid * 16 + i * 64][0]);
      }
    }
    __syncthreads();
    #pragma unroll
    for (int s = 0; s < 2; ++s) {
      bf16x8 af[4], bf[4];
      #pragma unroll
      for (int t = 0; t < 4; ++t) {
        af[t] = *(const bf16x8*)&As[s][wm * 64 + t * 16 + ln][qd * 8];
        bf[t] = *(const bf16x8*)&Bs[s][wn * 64 + t * 16 + ln][qd * 8];
      }
      #pragma unroll
      for (int mt = 0; mt < 4; ++mt)
        #pragma unroll
        for (int nt = 0; nt < 4; ++nt)
          acc[mt][nt] = __builtin_amdgcn_mfma_f32_16x16x32_bf16(af[mt], bf[nt], acc[mt][nt], 0, 0, 0);
    }
    __syncthreads();
  }
  #pragma unroll
  for (int mt = 0; mt < 4; ++mt) {
    #pragma unroll
    for (int nt = 0; nt < 4; ++nt) {
      const int col = blockIdx.x * 128 + wn * 64 + nt * 16 + ln;
      const float bv = bias[col];
      #pragma unroll
      for (int i = 0; i < 4; ++i) {
        const int row = blockIdx.y * 128 + wm * 64 + mt * 16 + qd * 4 + i;
        float v = acc[mt][nt][i] + bv;
        if (ACT) v = 0.5f * v * (1.f + erff(v * 0.70710678118654752f));
        if (WOUT == 1) {
          C[(size_t)row * N + col] = v;
        } else if (WOUT == 2) {
          if (col < 2 * D_) Cb[(size_t)row * N + col] = __float2bfloat16(v);
          else              vt[(size_t)(col - 2 * D_) * TP_ + row] = __float2bfloat16(v);
        } else {
          Cb[(size_t)row * N + col] = __float2bfloat16(v);
        }
      }
    }
  }
}

// ---------------------------------------------------------------------------
// 64x64 MFMA GEMM (for FF2: N=768 keeps the grid at 216 blocks)
// ---------------------------------------------------------------------------
template <int ACT, int WF32>
__global__ __launch_bounds__(256) void gemm_mfma64(
    const __hip_bfloat16* __restrict__ A,   // [MP,K]
    const __hip_bfloat16* __restrict__ Bt,  // [N,K]
    const float* __restrict__ bias,
    float* __restrict__ C, __hip_bfloat16* __restrict__ Cb,
    int N, int K) {
  __shared__ __align__(16) __hip_bfloat16 As[4][64][32];
  __shared__ __align__(16) __hip_bfloat16 Bs[4][64][32];
  const int tid  = threadIdx.x;
  const int lane = tid & 63, wid = tid >> 6;
  const int ln   = lane & 15, qd = lane >> 4;
  const int wm   = wid >> 1, wn = wid & 1;

  const size_t arow = (size_t)(blockIdx.y * 64 + wid * 16 + (lane >> 2)) * K + (lane & 3) * 8;
  const size_t brow = (size_t)(blockIdx.x * 64 + wid * 16 + (lane >> 2)) * K + (lane & 3) * 8;

  f32x4 acc[2][2] = {};
  for (int k0 = 0; k0 < K; k0 += 128) {
    #pragma unroll
    for (int s = 0; s < 4; ++s) {
      async_load16(A  + arow + k0 + s * 32, &As[s][wid * 16][0]);
      async_load16(Bt + brow + k0 + s * 32, &Bs[s][wid * 16][0]);
    }
    __syncthreads();
    #pragma unroll
    for (int s = 0; s < 4; ++s) {
      bf16x8 a0 = *(const bf16x8*)&As[s][wm * 32 + ln][qd * 8];
      bf16x8 a1 = *(const bf16x8*)&As[s][wm * 32 + 16 + ln][qd * 8];
      bf16x8 b0 = *(const bf16x8*)&Bs[s][wn * 32 + ln][qd * 8];
      bf16x8 b1 = *(const bf16x8*)&Bs[s][wn * 32 + 16 + ln][qd * 8];
      acc[0][0] = __builtin_amdgcn_mfma_f32_16x16x32_bf16(a0, b0, acc[0][0], 0, 0, 0);
      acc[0][1] = __builtin_amdgcn_mfma_f32_16x16x32_bf16(a0, b1, acc[0][1], 0, 0, 0);
      acc[1][0] = __builtin_amdgcn_mfma_f32_16x16x32_bf16(a1, b0, acc[1][0], 0, 0, 0);
      acc[1][1] = __builtin_amdgcn_mfma_f32_16x16x32_bf16(a1, b1, acc[1][1], 0, 0, 0);
    }
    __syncthreads();
  }
  #pragma unroll
  for (int mt = 0; mt < 2; ++mt) {
    #pragma unroll
    for (int nt = 0; nt < 2; ++nt) {
      const int col = blockIdx.x * 64 + wn * 32 + nt * 16 + ln;
      const float bv = bias[col];
      #pragma unroll
      for (int i = 0; i < 4; ++i) {
        const int row = blockIdx.y * 64 + wm * 32 + mt * 16 + qd * 4 + i;
        float v = acc[mt][nt][i] + bv;
        if (ACT) v = 0.5f * v * (1.f + erff(v * 0.70710678118654752f));
        if (WF32) C[(size_t)row * N + col]  = v;
        else      Cb[(size_t)row * N + col] = __float2bfloat16(v);
      }
    }
  }
}

// ---------------------------------------------------------------------------
// MFMA attention. grid = (5 q-tiles, 12 heads, 4 batches), 4 waves/block.
// Keys: 0..255 = seq tokens, 256/257 = memory, >=258 pad. No barriers.
// ---------------------------------------------------------------------------
__global__ __launch_bounds__(256) void attn_mfma(
    const __hip_bfloat16* __restrict__ qkv,  // [TP_][QS_]
    const __hip_bfloat16* __restrict__ vtb,  // [768][TP_]
    float* __restrict__ ctx) {               // [TP_][D_]
  __shared__ __align__(16) __hip_bfloat16 Ps[64][PS_];
  const int qt = blockIdx.x, h = blockIdx.y, b = blockIdx.z;
  const int tid = threadIdx.x;
  const int w = tid >> 6, lane = tid & 63, ln = lane & 15, qd = lane >> 4;

  bf16x8 aq0, aq1;
  {
    int j = qt * 64 + w * 16 + ln;
    int tok = (j < 256) ? (BASE_ + b * L_ + j)
            : ((j < KK_) ? (b * M_ + (j - 256)) : (b * M_));
    const __hip_bfloat16* qp = qkv + (size_t)tok * QS_ + h * DH_ + qd * 8;
    aq0 = *(const bf16x8*)qp;
    aq1 = *(const bf16x8*)(qp + 32);
  }

  f32x4 sa[17];
  #pragma unroll
  for (int nt = 0; nt < 17; ++nt) sa[nt] = (f32x4){0.f, 0.f, 0.f, 0.f};
  #pragma unroll
  for (int nt = 0; nt < 17; ++nt) {
    int key = nt * 16 + ln;
    int ktok = (key < 256) ? (BASE_ + b * L_ + key)
             : ((key < KK_) ? (b * M_ + (key - 256)) : (b * M_));
    const __hip_bfloat16* kp = qkv + (size_t)ktok * QS_ + D_ + h * DH_ + qd * 8;
    bf16x8 b0 = *(const bf16x8*)kp;
    bf16x8 b1 = *(const bf16x8*)(kp + 32);
    sa[nt] = __builtin_amdgcn_mfma_f32_16x16x32_bf16(aq0, b0, sa[nt], 0, 0, 0);
    sa[nt] = __builtin_amdgcn_mfma_f32_16x16x32_bf16(aq1, b1, sa[nt], 0, 0, 0);
  }

  #pragma unroll
  for (int i = 0; i < 4; ++i) {
    float v[17];
    #pragma unroll
    for (int nt = 0; nt < 17; ++nt) v[nt] = sa[nt][i] * 0.125f;
    float mx = -1e30f;
    #pragma unroll
    for (int nt = 0; nt < 16; ++nt) mx = fmaxf(mx, v[nt]);
    if (ln < 2) mx = fmaxf(mx, v[16]);
    #pragma unroll
    for (int m = 1; m < 16; m <<= 1) mx = fmaxf(mx, __shfl_xor(mx, m));
    float sum = 0.f;
    #pragma unroll
    for (int nt = 0; nt < 17; ++nt) {
      float e = (nt == 16 && ln >= 2) ? 0.f : __expf(v[nt] - mx);
      v[nt] = e;
      sum += e;
    }
    #pragma unroll
    for (int m = 1; m < 16; m <<= 1) sum += __shfl_xor(sum, m);
    float is = 1.f / sum;
    const int row = w * 16 + qd * 4 + i;
    #pragma unroll
    for (int nt = 0; nt < 17; ++nt)
      if (nt < 16 || ln < 2)
        Ps[row][nt * 16 + ln] = __float2bfloat16(v[nt] * is);
  }

  f32x4 oa[4] = {};
  #pragma unroll
  for (int k0 = 0; k0 < 8; ++k0) {
    bf16x8 ap = *(const bf16x8*)&Ps[w * 16 + ln][k0 * 32 + qd * 8];
    #pragma unroll
    for (int nt = 0; nt < 4; ++nt) {
      const __hip_bfloat16* vp = vtb + (size_t)(h * DH_ + nt * 16 + ln) * TP_
                               + BASE_ + b * L_ + k0 * 32 + qd * 8;
      bf16x8 bv = *(const bf16x8*)vp;
      oa[nt] = __builtin_amdgcn_mfma_f32_16x16x32_bf16(ap, bv, oa[nt], 0, 0, 0);
    }
  }
  {
    float p0[4], p1[4];
    #pragma unroll
    for (int i = 0; i < 4; ++i) {
      p0[i] = __bfloat162float(Ps[w * 16 + qd * 4 + i][256]);
      p1[i] = __bfloat162float(Ps[w * 16 + qd * 4 + i][257]);
    }
    #pragma unroll
    for (int nt = 0; nt < 4; ++nt) {
      const __hip_bfloat16* vp = vtb + (size_t)(h * DH_ + nt * 16 + ln) * TP_ + b * M_;
      float v0 = __bfloat162float(vp[0]);
      float v1 = __bfloat162float(vp[1]);
      #pragma unroll
      for (int i = 0; i < 4; ++i) oa[nt][i] += p0[i] * v0 + p1[i] * v1;
    }
  }

  #pragma unroll
  for (int i = 0; i < 4; ++i) {
    int j = qt * 64 + w * 16 + qd * 4 + i;
    if (j < KK_) {
      int tok = (j < 256) ? (BASE_ + b * L_ + j) : (b * M_ + (j - 256));
      #pragma unroll
      for (int nt = 0; nt < 4; ++nt)
        ctx[(size_t)tok * D_ + h * DH_ + nt * 16 + ln] = oa[nt][i];
    }
  }
}

// ---------------------------------------------------------------------------
__global__ __launch_bounds__(256) void add_ln_kernel(
    float* __restrict__ x, const float* __restrict__ delta,
    const float* __restrict__ g, const float* __restrict__ b,
    __hip_bfloat16* __restrict__ xb) {
  __shared__ float sred[4];
  __shared__ float sbc;
  const int t = blockIdx.x, tid = threadIdx.x;
  float y[3];
  float s = 0.f;
  #pragma unroll
  for (int i = 0; i < 3; ++i) {
    int d = tid + i * 256;
    y[i] = x[(long long)t * D_ + d] + delta[(long long)t * D_ + d];
    s += y[i];
  }
  #pragma unroll
  for (int o = 32; o > 0; o >>= 1) s += __shfl_down(s, o);
  if ((tid & 63) == 0) sred[tid >> 6] = s;
  __syncthreads();
  if (tid == 0) sbc = (sred[0] + sred[1] + sred[2] + sred[3]) * (1.f / D_);
  __syncthreads();
  const float mu = sbc;
  __syncthreads();
  float vs = 0.f;
  #pragma unroll
  for (int i = 0; i < 3; ++i) { float d = y[i] - mu; vs += d * d; }
  #pragma unroll
  for (int o = 32; o > 0; o >>= 1) vs += __shfl_down(vs, o);
  if ((tid & 63) == 0) sred[tid >> 6] = vs;
  __syncthreads();
  if (tid == 0) sbc = (sred[0] + sred[1] + sred[2] + sred[3]) * (1.f / D_);
  __syncthreads();
  const float inv = rsqrtf(sbc + 1e-5f);
  #pragma unroll
  for (int i = 0; i < 3; ++i) {
    int d = tid + i * 256;
    float v = (y[i] - mu) * inv * g[d] + b[d];
    x[(long long)t * D_ + d]  = v;
    xb[(long long)t * D_ + d] = __float2bfloat16(v);
  }
}

__global__ __launch_bounds__(256) void out_copy_kernel(
    const float* __restrict__ x, float* __restrict__ out, int n) {
  int i = blockIdx.x * 256 + threadIdx.x;
  if (i < n) out[i] = x[BASE_ * D_ + i];
}

// ---------------------------------------------------------------------------
extern "C" void kernel_launch(void* const* d_in, const int* in_sizes, int n_in,
                              void* d_out, int out_size, void* d_ws, size_t ws_size,
                              hipStream_t stream) {
  const int*   ids    = (const int*)  d_in[0];
  const float* memory = (const float*)d_in[1];
  const float* emb    = (const float*)d_in[2];
  const float* pos    = (const float*)d_in[3];
  const float* Wq     = (const float*)d_in[4];
  const float* bq     = (const float*)d_in[5];
  const float* Wk     = (const float*)d_in[6];
  const float* bk     = (const float*)d_in[7];
  const float* Wv     = (const float*)d_in[8];
  const float* bv     = (const float*)d_in[9];
  const float* W1     = (const float*)d_in[10];
  const float* b1     = (const float*)d_in[11];
  const float* W2     = (const float*)d_in[12];
  const float* b2     = (const float*)d_in[13];
  const float* g1     = (const float*)d_in[14];
  const float* be1    = (const float*)d_in[15];
  const float* g2     = (const float*)d_in[16];
  const float* be2    = (const float*)d_in[17];

  char* w = (char*)d_ws;
  float* x    = (float*)w;                      w += (size_t)TP_ * D_ * 4;
  float* cb   = (float*)w;                      w += (size_t)TP_ * D_ * 4;
  float* bqkv = (float*)w;                      w += (size_t)LAYERS_ * QS_ * 4;
  __hip_bfloat16* xb    = (__hip_bfloat16*)w;   w += (size_t)TP_ * D_ * 2;
  __hip_bfloat16* qkvb  = (__hip_bfloat16*)w;   w += (size_t)TP_ * QS_ * 2;
  __hip_bfloat16* vtb   = (__hip_bfloat16*)w;   w += (size_t)D_ * TP_ * 2;
  __hip_bfloat16* hbb   = (__hip_bfloat16*)w;   w += (size_t)TP_ * FF_ * 2;
  __hip_bfloat16* Wqkvt = (__hip_bfloat16*)w;   w += (size_t)LAYERS_ * QS_ * D_ * 2;
  __hip_bfloat16* W1t   = (__hip_bfloat16*)w;   w += (size_t)LAYERS_ * FF_ * D_ * 2;
  __hip_bfloat16* W2t   = (__hip_bfloat16*)w;   w += (size_t)LAYERS_ * D_ * FF_ * 2;

  prep_qkv_kernel<<<dim3(D_ / 32, D_ / 32, LAYERS_ * 3), 256, 0, stream>>>(Wq, Wk, Wv, Wqkvt);
  prep_w1_kernel<<<dim3(FF_ / 32, D_ / 32, LAYERS_), 256, 0, stream>>>(W1, W1t);
  prep_w2_kernel<<<dim3(D_ / 32, FF_ / 32, LAYERS_), 256, 0, stream>>>(W2, W2t);
  pack_bias_kernel<<<LAYERS_ * QS_ / 256, 256, 0, stream>>>(bq, bk, bv, bqkv);

  embed_kernel<<<T_, 256, 0, stream>>>(ids, memory, emb, pos, x, xb);

  for (int i = 0; i < LAYERS_; ++i) {
    gemm_mfma128<0, 2><<<dim3(QS_ / 128, TP_ / 128), 256, 0, stream>>>(
        xb, Wqkvt + (size_t)i * QS_ * D_, bqkv + i * QS_, nullptr, qkvb, vtb, QS_, D_);
    attn_mfma<<<dim3(5, H_, N_), 256, 0, stream>>>(qkvb, vtb, cb);
    add_ln_kernel<<<T_, 256, 0, stream>>>(x, cb, g1 + i * D_, be1 + i * D_, xb);
    gemm_mfma128<1, 0><<<dim3(FF_ / 128, TP_ / 128), 256, 0, stream>>>(
        xb, W1t + (size_t)i * FF_ * D_, b1 + i * FF_, nullptr, hbb, nullptr, FF_, D_);
    gemm_mfma64<0, 1><<<dim3(D_ / 64, TP_ / 64), 256, 0, stream>>>(
        hbb, W2t + (size_t)i * D_ * FF_, b2 + i * D_, cb, nullptr, D_, FF_);
    add_ln_kernel<<<T_, 256, 0, stream>>>(x, cb, g2 + i * D_, be2 + i * D_, xb);
  }

  out_copy_kernel<<<(out_size + 255) / 256, 256, 0, stream>>>(x, (float*)d_out, out_size);
}